// Round 3
// baseline (1466.431 us; speedup 1.0000x reference)
//
#include <hip/hip_runtime.h>

// GCN_90778428768712: 2-layer GCN on MI355X.
// x:[N,256] f32, edge_index:[2,E] int32 (src row 0, dst row 1),
// w1:[256,32], b1:[32], w2:[32,64], b2:[64]. Out: log_softmax(h2) [N,64] f32.

constexpr int NN   = 100000;
constexpr int EE   = 3200000;
constexpr int INC  = 256;
constexpr int HIDC = 32;
constexpr int OUTC = 64;

// ---- degree via float atomics -------------------------------------------
__global__ __launch_bounds__(256) void deg_kernel(const int* __restrict__ dst,
                                                  float* __restrict__ deg, int E) {
    int i = blockIdx.x * 256 + threadIdx.x;
    if (i < E) unsafeAtomicAdd(&deg[dst[i]], 1.0f);
}

__global__ __launch_bounds__(256) void dinv_kernel(const float* __restrict__ deg,
                                                   float* __restrict__ dinv, int n) {
    int i = blockIdx.x * 256 + threadIdx.x;
    if (i < n) {
        float d = deg[i];
        dinv[i] = d > 0.f ? rsqrtf(d) : 0.f;
    }
}

// ---- GEMM1: h1 = x @ w1  (N x 256 @ 256 x 32) ---------------------------
// 8 rows per 256-thread block; group g = tid>>5 owns row, lane = col.
__global__ __launch_bounds__(256) void gemm1_kernel(const float* __restrict__ x,
                                                    const float* __restrict__ w1,
                                                    float* __restrict__ h1) {
    __shared__ float ws[INC * HIDC];   // 32 KiB
    __shared__ float xs[8][INC];       // 8 KiB
    int t = threadIdx.x;
    for (int i = t; i < INC * HIDC; i += 256) ws[i] = w1[i];
    int row0 = blockIdx.x * 8;
    const float4* x4 = reinterpret_cast<const float4*>(x + (size_t)row0 * INC);
    float4* xs4 = reinterpret_cast<float4*>(&xs[0][0]);
    xs4[t]       = x4[t];
    xs4[t + 256] = x4[t + 256];
    __syncthreads();
    int g = t >> 5;
    int col = t & 31;
    float acc = 0.f;
#pragma unroll 8
    for (int k = 0; k < INC; ++k)
        acc = fmaf(xs[g][k], ws[k * HIDC + col], acc);
    h1[(size_t)(row0 + g) * HIDC + col] = acc;
}

// ---- edge aggregation, F=32: 32 lanes per edge --------------------------
__global__ __launch_bounds__(256) void agg32_kernel(const int* __restrict__ src,
                                                    const int* __restrict__ dst,
                                                    const float* __restrict__ dinv,
                                                    const float* __restrict__ h,
                                                    float* __restrict__ agg, int E) {
    int tid = blockIdx.x * 256 + threadIdx.x;   // < E*32 = 102.4M
    int e = tid >> 5;
    if (e >= E) return;
    int f = tid & 31;
    int s = src[e], d = dst[e];
    float nrm = dinv[s] * dinv[d];
    float v = h[(size_t)s * HIDC + f] * nrm;
    unsafeAtomicAdd(&agg[(size_t)d * HIDC + f], v);
}

// ---- bias + ReLU, in place over agg1 ------------------------------------
__global__ __launch_bounds__(256) void relu_bias_kernel(float* __restrict__ a,
                                                        const float* __restrict__ b,
                                                        int total) {
    int i = blockIdx.x * 256 + threadIdx.x;
    if (i < total) {
        float v = a[i] + b[i & (HIDC - 1)];
        a[i] = v > 0.f ? v : 0.f;
    }
}

// ---- GEMM2: g = h1a @ w2  (N x 32 @ 32 x 64) ----------------------------
// 4 rows per 256-thread block; wave wv owns row, lane = col.
__global__ __launch_bounds__(256) void gemm2_kernel(const float* __restrict__ h,
                                                    const float* __restrict__ w2,
                                                    float* __restrict__ g) {
    __shared__ float ws[HIDC * OUTC];  // 8 KiB
    __shared__ float xs[4][HIDC];
    int t = threadIdx.x;
    for (int i = t; i < HIDC * OUTC; i += 256) ws[i] = w2[i];
    int wv = t >> 6, lane = t & 63;
    int row = blockIdx.x * 4 + wv;
    if (lane < HIDC) xs[wv][lane] = h[(size_t)row * HIDC + lane];
    __syncthreads();
    float acc = 0.f;
#pragma unroll
    for (int k = 0; k < HIDC; ++k)
        acc = fmaf(xs[wv][k], ws[k * OUTC + lane], acc);
    g[(size_t)row * OUTC + lane] = acc;
}

// ---- edge aggregation, F=64: one wave per edge --------------------------
__global__ __launch_bounds__(256) void agg64_kernel(const int* __restrict__ src,
                                                    const int* __restrict__ dst,
                                                    const float* __restrict__ dinv,
                                                    const float* __restrict__ g,
                                                    float* __restrict__ agg, int E) {
    int tid = blockIdx.x * 256 + threadIdx.x;   // < E*64 = 204.8M
    int e = tid >> 6;
    if (e >= E) return;
    int f = tid & 63;
    int s = src[e], d = dst[e];
    float nrm = dinv[s] * dinv[d];
    float v = g[(size_t)s * OUTC + f] * nrm;
    unsafeAtomicAdd(&agg[(size_t)d * OUTC + f], v);
}

// ---- bias + log_softmax over 64 cols, one wave per row ------------------
__global__ __launch_bounds__(256) void lsm_kernel(float* __restrict__ out,
                                                  const float* __restrict__ b2, int n) {
    int t = threadIdx.x;
    int wv = t >> 6, lane = t & 63;
    int row = blockIdx.x * 4 + wv;
    if (row >= n) return;
    float v = out[(size_t)row * OUTC + lane] + b2[lane];
    float m = v;
#pragma unroll
    for (int off = 32; off; off >>= 1)
        m = fmaxf(m, __shfl_xor(m, off));
    float ex = expf(v - m);
    float sm = ex;
#pragma unroll
    for (int off = 32; off; off >>= 1)
        sm += __shfl_xor(sm, off);
    out[(size_t)row * OUTC + lane] = v - m - logf(sm);
}

extern "C" void kernel_launch(void* const* d_in, const int* in_sizes, int n_in,
                              void* d_out, int out_size, void* d_ws, size_t ws_size,
                              hipStream_t stream) {
    const float* x  = (const float*)d_in[0];
    const int*   ei = (const int*)d_in[1];
    const float* w1 = (const float*)d_in[2];
    const float* b1 = (const float*)d_in[3];
    const float* w2 = (const float*)d_in[4];
    const float* b2 = (const float*)d_in[5];
    float* out = (float*)d_out;

    const int n = NN, E = EE;
    const int* src = ei;
    const int* dst = ei + E;

    // workspace layout (floats): [deg N][agg1 32N] (zeroed together) [dinv N][h1 32N][g 64N]
    float* wsf  = (float*)d_ws;
    float* deg  = wsf;
    float* agg1 = wsf + n;
    float* dinv = agg1 + (size_t)n * HIDC;
    float* h1   = dinv + n;
    float* g    = h1 + (size_t)n * HIDC;

    hipMemsetAsync(deg, 0, sizeof(float) * (size_t)n * (1 + HIDC), stream);
    hipMemsetAsync(out, 0, sizeof(float) * (size_t)n * OUTC, stream);

    deg_kernel<<<(E + 255) / 256, 256, 0, stream>>>(dst, deg, E);
    dinv_kernel<<<(n + 255) / 256, 256, 0, stream>>>(deg, dinv, n);
    gemm1_kernel<<<n / 8, 256, 0, stream>>>(x, w1, h1);
    agg32_kernel<<<(int)(((long long)E * HIDC + 255) / 256), 256, 0, stream>>>(
        src, dst, dinv, h1, agg1, E);
    relu_bias_kernel<<<(n * HIDC + 255) / 256, 256, 0, stream>>>(agg1, b1, n * HIDC);
    gemm2_kernel<<<n / 4, 256, 0, stream>>>(agg1, w2, g);
    agg64_kernel<<<(int)(((long long)E * OUTC + 255) / 256), 256, 0, stream>>>(
        src, dst, dinv, g, out, E);
    lsm_kernel<<<n / 4, 256, 0, stream>>>(out, b2, n);
}

// Round 5
// 783.562 us; speedup vs baseline: 1.8715x; 1.8715x over previous
//
#include <hip/hip_runtime.h>

// GCN_90778428768712: 2-layer GCN, CSR pull-mode aggregation (no float atomics).
// x:[N,256] f32, edge_index:[2,E] int32 (src row 0, dst row 1),
// w1:[256,32], b1:[32], w2:[32,64], b2:[64]. Out: log_softmax(h2) [N,64] f32.

constexpr int NN   = 100000;
constexpr int EE   = 3200000;
constexpr int INC  = 256;
constexpr int HIDC = 32;
constexpr int OUTC = 64;

// ---- incoming-degree histogram ------------------------------------------
__global__ __launch_bounds__(256) void deg_kernel(const int* __restrict__ dst,
                                                  unsigned* __restrict__ deg, int E) {
    int i = blockIdx.x * 256 + threadIdx.x;
    if (i < E) atomicAdd(&deg[dst[i]], 1u);
}

__global__ __launch_bounds__(256) void dinv_kernel(const unsigned* __restrict__ deg,
                                                   float* __restrict__ dinv, int n) {
    int i = blockIdx.x * 256 + threadIdx.x;
    if (i < n) {
        unsigned d = deg[i];
        dinv[i] = d ? rsqrtf((float)d) : 0.f;
    }
}

// ---- 3-kernel exclusive scan of deg -> rowptr[n+1] ----------------------
// scan1: per-block (256) inclusive scan; rowptr[i+1] = local incl; aux[b] = block sum
__global__ __launch_bounds__(256) void scan1_kernel(const unsigned* __restrict__ deg,
                                                    int* __restrict__ rowptr,
                                                    unsigned* __restrict__ aux, int n) {
    __shared__ unsigned s[256];
    int t = threadIdx.x;
    int i = blockIdx.x * 256 + t;
    unsigned v = (i < n) ? deg[i] : 0u;
    s[t] = v;
    __syncthreads();
#pragma unroll
    for (int off = 1; off < 256; off <<= 1) {
        unsigned u = (t >= off) ? s[t - off] : 0u;
        __syncthreads();
        s[t] += u;
        __syncthreads();
    }
    if (i < n) rowptr[i + 1] = (int)s[t];
    if (t == 255) aux[blockIdx.x] = s[255];
}

// scan2: single block, exclusive scan of aux[nb] (nb <= 512)
__global__ __launch_bounds__(512) void scan2_kernel(unsigned* __restrict__ aux, int nb) {
    __shared__ unsigned s[512];
    int t = threadIdx.x;
    unsigned v = (t < nb) ? aux[t] : 0u;
    s[t] = v;
    __syncthreads();
#pragma unroll
    for (int off = 1; off < 512; off <<= 1) {
        unsigned u = (t >= off) ? s[t - off] : 0u;
        __syncthreads();
        s[t] += u;
        __syncthreads();
    }
    if (t < nb) aux[t] = s[t] - v;   // exclusive
}

// scan3: add block offsets; rowptr[0] = 0
__global__ __launch_bounds__(256) void scan3_kernel(int* __restrict__ rowptr,
                                                    const unsigned* __restrict__ aux, int n) {
    int i = blockIdx.x * 256 + threadIdx.x;
    if (i < n) rowptr[i + 1] += (int)aux[blockIdx.x];
    if (i == 0) rowptr[0] = 0;
}

// ---- scatter edges into CSR slots (int atomics on fill counters) --------
__global__ __launch_bounds__(256) void scatter_kernel(const int* __restrict__ src,
                                                      const int* __restrict__ dst,
                                                      const int* __restrict__ rowptr,
                                                      unsigned* __restrict__ fill,
                                                      int* __restrict__ srcS, int E) {
    int e = blockIdx.x * 256 + threadIdx.x;
    if (e >= E) return;
    int d = dst[e];
    int pos = rowptr[d] + (int)atomicAdd(&fill[d], 1u);
    srcS[pos] = src[e];
}

// ---- GEMM1: h1 = x @ w1  (N x 256 @ 256 x 32) ---------------------------
__global__ __launch_bounds__(256) void gemm1_kernel(const float* __restrict__ x,
                                                    const float* __restrict__ w1,
                                                    float* __restrict__ h1) {
    __shared__ float ws[INC * HIDC];   // 32 KiB
    __shared__ float xs[8][INC];       // 8 KiB
    int t = threadIdx.x;
    for (int i = t; i < INC * HIDC; i += 256) ws[i] = w1[i];
    int row0 = blockIdx.x * 8;
    const float4* x4 = reinterpret_cast<const float4*>(x + (size_t)row0 * INC);
    float4* xs4 = reinterpret_cast<float4*>(&xs[0][0]);
    xs4[t]       = x4[t];
    xs4[t + 256] = x4[t + 256];
    __syncthreads();
    int g = t >> 5;
    int col = t & 31;
    float acc = 0.f;
#pragma unroll 8
    for (int k = 0; k < INC; ++k)
        acc = fmaf(xs[g][k], ws[k * HIDC + col], acc);
    h1[(size_t)(row0 + g) * HIDC + col] = acc;
}

// ---- agg1 (pull) + bias + ReLU: 32 lanes per dst row --------------------
// acc_f = dinv[row] * sum_e dinv[src_e] * h1[src_e][f]
__global__ __launch_bounds__(256) void agg1_kernel(const int* __restrict__ rowptr,
                                                   const int* __restrict__ srcS,
                                                   const float* __restrict__ dinv,
                                                   const float* __restrict__ h1,
                                                   const float* __restrict__ b1,
                                                   float* __restrict__ h1a, int n) {
    int t = threadIdx.x;
    int grp = t >> 5, f = t & 31;
    int row = blockIdx.x * 8 + grp;
    if (row >= n) return;
    int e = rowptr[row], end = rowptr[row + 1];
    float acc = 0.f;
    for (; e + 4 <= end; e += 4) {
        int s0 = srcS[e], s1 = srcS[e + 1], s2 = srcS[e + 2], s3 = srcS[e + 3];
        float d0 = dinv[s0], d1 = dinv[s1], d2 = dinv[s2], d3 = dinv[s3];
        acc = fmaf(h1[(size_t)s0 * HIDC + f], d0, acc);
        acc = fmaf(h1[(size_t)s1 * HIDC + f], d1, acc);
        acc = fmaf(h1[(size_t)s2 * HIDC + f], d2, acc);
        acc = fmaf(h1[(size_t)s3 * HIDC + f], d3, acc);
    }
    for (; e < end; ++e) {
        int s = srcS[e];
        acc = fmaf(h1[(size_t)s * HIDC + f], dinv[s], acc);
    }
    float v = acc * dinv[row] + b1[f];
    h1a[(size_t)row * HIDC + f] = v > 0.f ? v : 0.f;
}

// ---- GEMM2: g = h1a @ w2  (N x 32 @ 32 x 64) ----------------------------
__global__ __launch_bounds__(256) void gemm2_kernel(const float* __restrict__ h,
                                                    const float* __restrict__ w2,
                                                    float* __restrict__ g) {
    __shared__ float ws[HIDC * OUTC];  // 8 KiB
    __shared__ float xs[4][HIDC];
    int t = threadIdx.x;
    for (int i = t; i < HIDC * OUTC; i += 256) ws[i] = w2[i];
    int wv = t >> 6, lane = t & 63;
    int row = blockIdx.x * 4 + wv;
    if (lane < HIDC) xs[wv][lane] = h[(size_t)row * HIDC + lane];
    __syncthreads();
    float acc = 0.f;
#pragma unroll
    for (int k = 0; k < HIDC; ++k)
        acc = fmaf(xs[wv][k], ws[k * OUTC + lane], acc);
    g[(size_t)row * OUTC + lane] = acc;
}

// ---- agg2 (pull) + bias + log_softmax: one wave per dst row -------------
__global__ __launch_bounds__(256) void agg2_lsm_kernel(const int* __restrict__ rowptr,
                                                       const int* __restrict__ srcS,
                                                       const float* __restrict__ dinv,
                                                       const float* __restrict__ g,
                                                       const float* __restrict__ b2,
                                                       float* __restrict__ out, int n) {
    int t = threadIdx.x;
    int wv = t >> 6, lane = t & 63;
    int row = blockIdx.x * 4 + wv;
    if (row >= n) return;
    int e = rowptr[row], end = rowptr[row + 1];
    float acc = 0.f;
    for (; e + 4 <= end; e += 4) {
        int s0 = srcS[e], s1 = srcS[e + 1], s2 = srcS[e + 2], s3 = srcS[e + 3];
        float d0 = dinv[s0], d1 = dinv[s1], d2 = dinv[s2], d3 = dinv[s3];
        acc = fmaf(g[(size_t)s0 * OUTC + lane], d0, acc);
        acc = fmaf(g[(size_t)s1 * OUTC + lane], d1, acc);
        acc = fmaf(g[(size_t)s2 * OUTC + lane], d2, acc);
        acc = fmaf(g[(size_t)s3 * OUTC + lane], d3, acc);
    }
    for (; e < end; ++e) {
        int s = srcS[e];
        acc = fmaf(g[(size_t)s * OUTC + lane], dinv[s], acc);
    }
    float v = acc * dinv[row] + b2[lane];
    float m = v;
#pragma unroll
    for (int off = 32; off; off >>= 1)
        m = fmaxf(m, __shfl_xor(m, off));
    float sm = expf(v - m);
#pragma unroll
    for (int off = 32; off; off >>= 1)
        sm += __shfl_xor(sm, off);
    out[(size_t)row * OUTC + lane] = v - m - logf(sm);
}

extern "C" void kernel_launch(void* const* d_in, const int* in_sizes, int n_in,
                              void* d_out, int out_size, void* d_ws, size_t ws_size,
                              hipStream_t stream) {
    const float* x  = (const float*)d_in[0];
    const int*   ei = (const int*)d_in[1];
    const float* w1 = (const float*)d_in[2];
    const float* b1 = (const float*)d_in[3];
    const float* w2 = (const float*)d_in[4];
    const float* b2 = (const float*)d_in[5];
    float* out = (float*)d_out;

    const int n = NN, E = EE;
    const int* src = ei;
    const int* dst = ei + E;

    // workspace layout (4-byte units):
    // [deg n][fill n] (zeroed together) [dinv n][rowptr n+1][aux 1024][srcS E][h1 32n][h1a 32n][g 64n]
    // total = 132n + E + 1025 floats ~= 65.6 MB
    unsigned* deg  = (unsigned*)d_ws;
    unsigned* fill = deg + n;
    float* dinv    = (float*)(fill + n);
    int* rowptr    = (int*)(dinv + n);
    unsigned* aux  = (unsigned*)(rowptr + n + 1);
    int* srcS      = (int*)(aux + 1024);
    float* h1      = (float*)(srcS + E);
    float* h1a     = h1 + (size_t)n * HIDC;
    float* g       = h1a + (size_t)n * HIDC;

    const int nbE = (E + 255) / 256;          // 12500
    const int nbN = (n + 255) / 256;          // 391

    hipMemsetAsync(deg, 0, sizeof(unsigned) * (size_t)2 * n, stream);

    deg_kernel<<<nbE, 256, 0, stream>>>(dst, deg, E);
    dinv_kernel<<<nbN, 256, 0, stream>>>(deg, dinv, n);
    scan1_kernel<<<nbN, 256, 0, stream>>>(deg, rowptr, aux, n);
    scan2_kernel<<<1, 512, 0, stream>>>(aux, nbN);
    scan3_kernel<<<nbN, 256, 0, stream>>>(rowptr, aux, n);
    scatter_kernel<<<nbE, 256, 0, stream>>>(src, dst, rowptr, fill, srcS, E);

    gemm1_kernel<<<n / 8, 256, 0, stream>>>(x, w1, h1);
    agg1_kernel<<<n / 8, 256, 0, stream>>>(rowptr, srcS, dinv, h1, b1, h1a, n);
    gemm2_kernel<<<n / 4, 256, 0, stream>>>(h1a, w2, g);
    agg2_lsm_kernel<<<n / 4, 256, 0, stream>>>(rowptr, srcS, dinv, g, b2, out, n);
}

// Round 9
// 729.800 us; speedup vs baseline: 2.0094x; 1.0737x over previous
//
#include <hip/hip_runtime.h>

// GCN_90778428768712: 2-layer GCN, CSR pull-mode. Layer-2 aggregation commuted
// into 32-dim space: out = logsoftmax((A_norm @ relu(A_norm@(x@w1)+b1)) @ w2 + b2).
// x:[N,256] f32, edge_index:[2,E] int32 (src row 0, dst row 1).

constexpr int NN   = 100000;
constexpr int EE   = 3200000;
constexpr int INC  = 256;
constexpr int HIDC = 32;
constexpr int OUTC = 64;

// ---- incoming-degree histogram ------------------------------------------
__global__ __launch_bounds__(256) void deg_kernel(const int* __restrict__ dst,
                                                  unsigned* __restrict__ deg, int E) {
    int i = blockIdx.x * 256 + threadIdx.x;
    if (i < E) atomicAdd(&deg[dst[i]], 1u);
}

__global__ __launch_bounds__(256) void dinv_kernel(const unsigned* __restrict__ deg,
                                                   float* __restrict__ dinv, int n) {
    int i = blockIdx.x * 256 + threadIdx.x;
    if (i < n) {
        unsigned d = deg[i];
        dinv[i] = d ? rsqrtf((float)d) : 0.f;
    }
}

// ---- 3-kernel exclusive scan of deg -> rowptr[n+1] ----------------------
__global__ __launch_bounds__(256) void scan1_kernel(const unsigned* __restrict__ deg,
                                                    int* __restrict__ rowptr,
                                                    unsigned* __restrict__ aux, int n) {
    __shared__ unsigned s[256];
    int t = threadIdx.x;
    int i = blockIdx.x * 256 + t;
    unsigned v = (i < n) ? deg[i] : 0u;
    s[t] = v;
    __syncthreads();
#pragma unroll
    for (int off = 1; off < 256; off <<= 1) {
        unsigned u = (t >= off) ? s[t - off] : 0u;
        __syncthreads();
        s[t] += u;
        __syncthreads();
    }
    if (i < n) rowptr[i + 1] = (int)s[t];
    if (t == 255) aux[blockIdx.x] = s[255];
}

__global__ __launch_bounds__(512) void scan2_kernel(unsigned* __restrict__ aux, int nb) {
    __shared__ unsigned s[512];
    int t = threadIdx.x;
    unsigned v = (t < nb) ? aux[t] : 0u;
    s[t] = v;
    __syncthreads();
#pragma unroll
    for (int off = 1; off < 512; off <<= 1) {
        unsigned u = (t >= off) ? s[t - off] : 0u;
        __syncthreads();
        s[t] += u;
        __syncthreads();
    }
    if (t < nb) aux[t] = s[t] - v;   // exclusive
}

__global__ __launch_bounds__(256) void scan3_kernel(int* __restrict__ rowptr,
                                                    const unsigned* __restrict__ aux, int n) {
    int i = blockIdx.x * 256 + threadIdx.x;
    if (i < n) rowptr[i + 1] += (int)aux[blockIdx.x];
    if (i == 0) rowptr[0] = 0;
}

// ---- scatter edges into CSR slots; payload = {src, dinv[src]} (8B) ------
__global__ __launch_bounds__(256) void scatter_kernel(const int* __restrict__ src,
                                                      const int* __restrict__ dst,
                                                      const int* __restrict__ rowptr,
                                                      const float* __restrict__ dinv,
                                                      unsigned* __restrict__ fill,
                                                      int2* __restrict__ srcS, int E) {
    int e = blockIdx.x * 256 + threadIdx.x;
    if (e >= E) return;
    int d = dst[e];
    int s = src[e];
    int pos = rowptr[d] + (int)atomicAdd(&fill[d], 1u);
    srcS[pos] = make_int2(s, __float_as_int(dinv[s]));
}

// ---- GEMM1: h1 = x @ w1  (N x 256 @ 256 x 32) ---------------------------
__global__ __launch_bounds__(256) void gemm1_kernel(const float* __restrict__ x,
                                                    const float* __restrict__ w1,
                                                    float* __restrict__ h1) {
    __shared__ float ws[INC * HIDC];   // 32 KiB
    __shared__ float xs[8][INC];       // 8 KiB
    int t = threadIdx.x;
    for (int i = t; i < INC * HIDC; i += 256) ws[i] = w1[i];
    int row0 = blockIdx.x * 8;
    const float4* x4 = reinterpret_cast<const float4*>(x + (size_t)row0 * INC);
    float4* xs4 = reinterpret_cast<float4*>(&xs[0][0]);
    xs4[t]       = x4[t];
    xs4[t + 256] = x4[t + 256];
    __syncthreads();
    int g = t >> 5;
    int col = t & 31;
    float acc = 0.f;
#pragma unroll 8
    for (int k = 0; k < INC; ++k)
        acc = fmaf(xs[g][k], ws[k * HIDC + col], acc);
    h1[(size_t)(row0 + g) * HIDC + col] = acc;
}

// ---- agg1 (pull) + bias + ReLU: 32 lanes per dst row, 8-deep MLP --------
__global__ __launch_bounds__(256) void agg1_kernel(const int* __restrict__ rowptr,
                                                   const int2* __restrict__ srcS,
                                                   const float* __restrict__ dinv,
                                                   const float* __restrict__ h1,
                                                   const float* __restrict__ b1,
                                                   float* __restrict__ h1a, int n) {
    int t = threadIdx.x;
    int grp = t >> 5, f = t & 31;
    int row = blockIdx.x * 8 + grp;
    if (row >= n) return;
    int e = rowptr[row], end = rowptr[row + 1];
    float acc = 0.f;
    for (; e + 8 <= end; e += 8) {
        int2 p0 = srcS[e],     p1 = srcS[e + 1], p2 = srcS[e + 2], p3 = srcS[e + 3];
        int2 p4 = srcS[e + 4], p5 = srcS[e + 5], p6 = srcS[e + 6], p7 = srcS[e + 7];
        float v0 = h1[(size_t)p0.x * HIDC + f], v1 = h1[(size_t)p1.x * HIDC + f];
        float v2 = h1[(size_t)p2.x * HIDC + f], v3 = h1[(size_t)p3.x * HIDC + f];
        float v4 = h1[(size_t)p4.x * HIDC + f], v5 = h1[(size_t)p5.x * HIDC + f];
        float v6 = h1[(size_t)p6.x * HIDC + f], v7 = h1[(size_t)p7.x * HIDC + f];
        acc = fmaf(v0, __int_as_float(p0.y), acc);
        acc = fmaf(v1, __int_as_float(p1.y), acc);
        acc = fmaf(v2, __int_as_float(p2.y), acc);
        acc = fmaf(v3, __int_as_float(p3.y), acc);
        acc = fmaf(v4, __int_as_float(p4.y), acc);
        acc = fmaf(v5, __int_as_float(p5.y), acc);
        acc = fmaf(v6, __int_as_float(p6.y), acc);
        acc = fmaf(v7, __int_as_float(p7.y), acc);
    }
    for (; e < end; ++e) {
        int2 p = srcS[e];
        acc = fmaf(h1[(size_t)p.x * HIDC + f], __int_as_float(p.y), acc);
    }
    float v = acc * dinv[row] + b1[f];
    h1a[(size_t)row * HIDC + f] = v > 0.f ? v : 0.f;
}

// ---- agg2 (pull) over h1a -> z2 [N,32], 8-deep MLP ----------------------
__global__ __launch_bounds__(256) void agg2_kernel(const int* __restrict__ rowptr,
                                                   const int2* __restrict__ srcS,
                                                   const float* __restrict__ dinv,
                                                   const float* __restrict__ h1a,
                                                   float* __restrict__ z2, int n) {
    int t = threadIdx.x;
    int grp = t >> 5, f = t & 31;
    int row = blockIdx.x * 8 + grp;
    if (row >= n) return;
    int e = rowptr[row], end = rowptr[row + 1];
    float acc = 0.f;
    for (; e + 8 <= end; e += 8) {
        int2 p0 = srcS[e],     p1 = srcS[e + 1], p2 = srcS[e + 2], p3 = srcS[e + 3];
        int2 p4 = srcS[e + 4], p5 = srcS[e + 5], p6 = srcS[e + 6], p7 = srcS[e + 7];
        float v0 = h1a[(size_t)p0.x * HIDC + f], v1 = h1a[(size_t)p1.x * HIDC + f];
        float v2 = h1a[(size_t)p2.x * HIDC + f], v3 = h1a[(size_t)p3.x * HIDC + f];
        float v4 = h1a[(size_t)p4.x * HIDC + f], v5 = h1a[(size_t)p5.x * HIDC + f];
        float v6 = h1a[(size_t)p6.x * HIDC + f], v7 = h1a[(size_t)p7.x * HIDC + f];
        acc = fmaf(v0, __int_as_float(p0.y), acc);
        acc = fmaf(v1, __int_as_float(p1.y), acc);
        acc = fmaf(v2, __int_as_float(p2.y), acc);
        acc = fmaf(v3, __int_as_float(p3.y), acc);
        acc = fmaf(v4, __int_as_float(p4.y), acc);
        acc = fmaf(v5, __int_as_float(p5.y), acc);
        acc = fmaf(v6, __int_as_float(p6.y), acc);
        acc = fmaf(v7, __int_as_float(p7.y), acc);
    }
    for (; e < end; ++e) {
        int2 p = srcS[e];
        acc = fmaf(h1a[(size_t)p.x * HIDC + f], __int_as_float(p.y), acc);
    }
    z2[(size_t)row * HIDC + f] = acc * dinv[row];
}

// ---- fused gemm2 + bias + log_softmax: out = lsm(z2 @ w2 + b2) ----------
__global__ __launch_bounds__(256) void gemmlsm_kernel(const float* __restrict__ z2,
                                                      const float* __restrict__ w2,
                                                      const float* __restrict__ b2,
                                                      float* __restrict__ out, int n) {
    __shared__ float ws[HIDC * OUTC];  // 8 KiB
    __shared__ float zs[4][HIDC];
    int t = threadIdx.x;
    for (int i = t; i < HIDC * OUTC; i += 256) ws[i] = w2[i];
    int row0 = blockIdx.x * 4;
    if (t < 4 * HIDC) zs[t >> 5][t & 31] = z2[(size_t)row0 * HIDC + t];
    __syncthreads();
    int wv = t >> 6, lane = t & 63;
    int row = row0 + wv;
    if (row >= n) return;
    float acc = 0.f;
#pragma unroll
    for (int k = 0; k < HIDC; ++k)
        acc = fmaf(zs[wv][k], ws[k * OUTC + lane], acc);
    float v = acc + b2[lane];
    float m = v;
#pragma unroll
    for (int off = 32; off; off >>= 1)
        m = fmaxf(m, __shfl_xor(m, off));
    float sm = expf(v - m);
#pragma unroll
    for (int off = 32; off; off >>= 1)
        sm += __shfl_xor(sm, off);
    out[(size_t)row * OUTC + lane] = v - m - logf(sm);
}

extern "C" void kernel_launch(void* const* d_in, const int* in_sizes, int n_in,
                              void* d_out, int out_size, void* d_ws, size_t ws_size,
                              hipStream_t stream) {
    const float* x  = (const float*)d_in[0];
    const int*   ei = (const int*)d_in[1];
    const float* w1 = (const float*)d_in[2];
    const float* b1 = (const float*)d_in[3];
    const float* w2 = (const float*)d_in[4];
    const float* b2 = (const float*)d_in[5];
    float* out = (float*)d_out;

    const int n = NN, E = EE;
    const int* src = ei;
    const int* dst = ei + E;

    // workspace layout (4-byte units):
    // [deg n][fill n] (zeroed together) [dinv n][rowptr n+1][aux 1024][srcS8 2E][h1 32n][h1a 32n][z2 32n]
    // total ~= 53 MB
    unsigned* deg  = (unsigned*)d_ws;
    unsigned* fill = deg + n;
    float* dinv    = (float*)(fill + n);
    int* rowptr    = (int*)(dinv + n);
    unsigned* aux  = (unsigned*)(rowptr + n + 1);
    int2* srcS     = (int2*)(aux + 1024);
    float* h1      = (float*)(srcS + E);
    float* h1a     = h1 + (size_t)n * HIDC;
    float* z2      = h1a + (size_t)n * HIDC;

    const int nbE = (E + 255) / 256;          // 12500
    const int nbN = (n + 255) / 256;          // 391

    hipMemsetAsync(deg, 0, sizeof(unsigned) * (size_t)2 * n, stream);

    deg_kernel<<<nbE, 256, 0, stream>>>(dst, deg, E);
    dinv_kernel<<<nbN, 256, 0, stream>>>(deg, dinv, n);
    scan1_kernel<<<nbN, 256, 0, stream>>>(deg, rowptr, aux, n);
    scan2_kernel<<<1, 512, 0, stream>>>(aux, nbN);
    scan3_kernel<<<nbN, 256, 0, stream>>>(rowptr, aux, n);
    scatter_kernel<<<nbE, 256, 0, stream>>>(src, dst, rowptr, dinv, fill, srcS, E);

    gemm1_kernel<<<n / 8, 256, 0, stream>>>(x, w1, h1);
    agg1_kernel<<<n / 8, 256, 0, stream>>>(rowptr, srcS, dinv, h1, b1, h1a, n);
    agg2_kernel<<<n / 8, 256, 0, stream>>>(rowptr, srcS, dinv, h1a, z2, n);
    gemmlsm_kernel<<<n / 4, 256, 0, stream>>>(z2, w2, b2, out, n);
}